// Round 9
// baseline (170.734 us; speedup 1.0000x reference)
//
#include <hip/hip_runtime.h>
#include <cstdint>
#include <cstddef>

// Problem constants
#define NCB   8
#define KC    1024
#define SDIM  64
#define LDIM  512          // NCB*SDIM
#define BATCH 8192
#define INV_TAU (1.0f/0.07f)
#define K2E  20.60992915555662f   // log2(e)/TAU
#define DBIAS 256.0f           // dist bias: dist+256 in [174,466) -> positive, 2 binades

typedef __bf16 bf16_t;
typedef bf16_t bf16x8 __attribute__((ext_vector_type(8)));
typedef float  floatx4 __attribute__((ext_vector_type(4)));
typedef int    intx8  __attribute__((ext_vector_type(8)));
typedef unsigned int u32;

__device__ __forceinline__ unsigned short f2bf(float f) {
    union { float f; unsigned int u; } c; c.f = f;
    unsigned int u = c.u;
    u += 0x7fffu + ((u >> 16) & 1u);   // round-to-nearest-even
    return (unsigned short)(u >> 16);
}
__device__ __forceinline__ float bf2f(unsigned short h) {
    union { unsigned int u; float f; } c; c.u = ((unsigned int)h) << 16;
    return c.f;
}
__device__ __forceinline__ float exp2_fast(float x) {
    float r; asm("v_exp_f32 %0, %1" : "=v"(r) : "v"(x)); return r;
}
// async global->LDS DMA, 16B/lane. LDS dest = wave-uniform base + lane*16 (linear).
__device__ __forceinline__ void gll16(const void* g, void* l) {
    __builtin_amdgcn_global_load_lds(
        (const __attribute__((address_space(1))) u32*)g,
        (__attribute__((address_space(3))) u32*)l,
        16, 0, 0);
}

// ---------------------------------------------------------------------------
// K0: embeddings: e2 + bf16 hi/lo split + zero accs. 256 blocks, 8 lanes/row.
// ---------------------------------------------------------------------------
__global__ __launch_bounds__(256) void
k_pre(const float* __restrict__ emb, float* __restrict__ e2,
      unsigned short* __restrict__ eh, unsigned short* __restrict__ el,
      float* __restrict__ accs) {
    int gid = blockIdx.x * 256 + threadIdx.x;   // 0..65535
    int row = gid >> 3, g = gid & 7;            // row 0..8191, 8 floats/lane
    const float4* e4 = (const float4*)(emb + (size_t)row*SDIM + g*8);
    float4 a = e4[0], b = e4[1];
    union { ushort4 u4[2]; uint4 v; } H, L;
    H.u4[0].x=f2bf(a.x); L.u4[0].x=f2bf(a.x-bf2f(H.u4[0].x));
    H.u4[0].y=f2bf(a.y); L.u4[0].y=f2bf(a.y-bf2f(H.u4[0].y));
    H.u4[0].z=f2bf(a.z); L.u4[0].z=f2bf(a.z-bf2f(H.u4[0].z));
    H.u4[0].w=f2bf(a.w); L.u4[0].w=f2bf(a.w-bf2f(H.u4[0].w));
    H.u4[1].x=f2bf(b.x); L.u4[1].x=f2bf(b.x-bf2f(H.u4[1].x));
    H.u4[1].y=f2bf(b.y); L.u4[1].y=f2bf(b.y-bf2f(H.u4[1].y));
    H.u4[1].z=f2bf(b.z); L.u4[1].z=f2bf(b.z-bf2f(H.u4[1].z));
    H.u4[1].w=f2bf(b.w); L.u4[1].w=f2bf(b.w-bf2f(H.u4[1].w));
    *(uint4*)(eh + (size_t)row*SDIM + g*8) = H.v;
    *(uint4*)(el + (size_t)row*SDIM + g*8) = L.v;
    float s = a.x*a.x + a.y*a.y + a.z*a.z + a.w*a.w
            + b.x*b.x + b.y*b.y + b.z*b.z + b.w*b.w;
    s += __shfl_xor(s, 1); s += __shfl_xor(s, 2); s += __shfl_xor(s, 4);
    if (g == 0) e2[row] = s;
    if (gid == 0){ accs[0]=0.f; accs[1]=0.f; accs[2]=0.f; }
}

// fp64 "relative distance" e2 - 2*z.e (z2 cancels in argmin ordering)
__device__ __forceinline__ double dist64d(const float* __restrict__ e,
                                          const float* __restrict__ zg) {
    double se=0.0, sz=0.0;
#pragma unroll 8
    for (int i=0;i<64;i++){ double ev=(double)e[i];
        se = fma(ev,ev,se); sz = fma(ev,(double)zg[i],sz); }
    return se - 2.0*sz;
}

// ---------------------------------------------------------------------------
// K2: MFMA argmin. R22: R6 structure (16 phases, 64-code B dbuf, plain
// __syncthreads — R8 proved counted-vmcnt == drain; the cost is barrier
// CONVERGENCE, hideable only by other resident blocks) with the block
// HALVED: 64-row tiles, grid (128,8) = 1024 blocks. LDS ~49.5 KB ->
// 3 blocks/CU resident (R5 lesson: occupancy needs BLOCKS, not just
// launch_bounds — 512-block grid capped at 2/CU). XCD pin n=bx&7 kept
// (128 % 8 == 0 -> wgid%8 == bx&7). Epilogue = R6 serial (R7's parallel
// rewrite was slower). B traffic doubles but is XCD-L2-resident (R6
// FETCH collapse proved the pin).
// ---------------------------------------------------------------------------
__global__ __launch_bounds__(256,3) void
k_argmin(const unsigned short* __restrict__ eh, const unsigned short* __restrict__ el,
         const float* __restrict__ e2, const float* __restrict__ z,
         const float* __restrict__ emb, float* __restrict__ out_q,
         float* __restrict__ out_idx, float* __restrict__ accs) {
    __shared__ __align__(16) unsigned short Ah[64*64], Al[64*64];      // 16 KB
    __shared__ __align__(16) unsigned short Bh[2][64*64], Bl[2][64*64];// 32 KB
    __shared__ float e2s[2][64];
    __shared__ unsigned int mK[2][64][2];

    const int tid = threadIdx.x;
    // XCD pin: n = bx&7 (== XCD id); row-tile from remaining bits.
    const int n   = blockIdx.x & 7;
    const int i0  = ((blockIdx.x >> 3) | (blockIdx.y << 4)) * 64;   // 0..127 tiles
    const int wid = tid >> 6, lane = tid & 63;
    const int wm = wid & 1, wn = wid >> 1;
    const int c  = lane & 15, qq = lane >> 4;

    // stage A (resident): read z fp32, split hi/lo in-kernel, swizzled store
#pragma unroll
    for (int s=0;s<4;s++){
        int seg = tid + s*256;           // 1024 segs; 16 float4-segs per row
        int r = seg >> 4, sg = seg & 15;
        float4 v = *(const float4*)(z + (size_t)(i0+r)*LDIM + n*SDIM + sg*4);
        ushort4 h, l;
        h.x=f2bf(v.x); l.x=f2bf(v.x-bf2f(h.x));
        h.y=f2bf(v.y); l.y=f2bf(v.y-bf2f(h.y));
        h.z=f2bf(v.z); l.z=f2bf(v.z-bf2f(h.z));
        h.w=f2bf(v.w); l.w=f2bf(v.w-bf2f(h.w));
        int off = r*64 + ((sg*4) ^ ((r&7)<<3));   // shorts; == byte XOR (r&7)<<4
        *(ushort4*)(&Ah[off]) = h;
        *(ushort4*)(&Al[off]) = l;
    }

    const unsigned char* ehb = (const unsigned char*)(eh + (size_t)n*KC*SDIM);
    const unsigned char* elb = (const unsigned char*)(el + (size_t)n*KC*SDIM);
    const float* e2n = e2 + n*KC;

    // gll lane geometry: 8 rows x 128B per wave-instr; source pre-swizzled
    const int brow = lane >> 3;                       // row-in-8
    const int bchk = ((lane & 7)*16) ^ (brow << 4);   // swizzled byte in row

    auto stageB = [&](int buf, int j0){
#pragma unroll
        for (int s=0;s<2;s++){
            int r0 = wid*16 + s*8;                    // multiple of 8
            size_t go = (size_t)(j0 + r0 + brow)*128 + bchk;
            gll16(ehb + go, &Bh[buf][r0*64]);
            gll16(elb + go, &Bl[buf][r0*64]);
        }
    };

    if (tid < 64) e2s[0][tid] = e2n[tid] + DBIAS;
    stageB(0, 0);

    unsigned int k1[8], k2[8];
#pragma unroll
    for (int j=0;j<8;j++){ k1[j]=0xFFFFFFFFu; k2[j]=0xFFFFFFFFu; }

    __syncthreads();

    for (int jt=0; jt<16; jt++){
        const int cur = jt & 1, nxt = cur ^ 1;
        const int j0 = jt*64;
        float e2r = 0.f;
        if (jt < 15){
            stageB(nxt, j0 + 64);                 // async prefetch next tile
            if (tid < 64) e2r = e2n[j0 + 64 + tid];
        }

        floatx4 acc[2][2];
#pragma unroll
        for (int mt=0;mt<2;mt++){
            acc[mt][0]=(floatx4){0.f,0.f,0.f,0.f};
            acc[mt][1]=(floatx4){0.f,0.f,0.f,0.f};
        }

#pragma unroll
        for (int t=0;t<2;t++){
            const int axo = (t*32 + qq*8) ^ ((c&7)<<3);   // shorts
            bf16x8 ah[2], alo[2], bh[2], bl[2];
#pragma unroll
            for (int mt=0;mt<2;mt++){
                int ro = (wm*32 + mt*16 + c)*64 + axo;
                ah[mt]  = *(const bf16x8*)(&Ah[ro]);
                alo[mt] = *(const bf16x8*)(&Al[ro]);
            }
#pragma unroll
            for (int nt=0;nt<2;nt++){
                int ro = (wn*32 + nt*16 + c)*64 + axo;
                bh[nt] = *(const bf16x8*)(&Bh[cur][ro]);
                bl[nt] = *(const bf16x8*)(&Bl[cur][ro]);
            }
#pragma unroll
            for (int mt=0;mt<2;mt++)
#pragma unroll
                for (int nt=0;nt<2;nt++){
                    acc[mt][nt] = __builtin_amdgcn_mfma_f32_16x16x32_bf16(ah[mt],  bh[nt], acc[mt][nt], 0,0,0);
                    acc[mt][nt] = __builtin_amdgcn_mfma_f32_16x16x32_bf16(ah[mt],  bl[nt], acc[mt][nt], 0,0,0);
                    acc[mt][nt] = __builtin_amdgcn_mfma_f32_16x16x32_bf16(alo[mt], bh[nt], acc[mt][nt], 0,0,0);
                }
        }

        // biased dist -> packed key -> branchless top-2 (min + med3)
#pragma unroll
        for (int nt=0;nt<2;nt++){
            const int colb = wn*32 + nt*16 + c;
            float e2v = e2s[cur][colb];
            unsigned int kidx = (unsigned int)(j0 + colb);
#pragma unroll
            for (int mt=0;mt<2;mt++)
#pragma unroll
                for (int reg=0;reg<4;reg++){
                    float d = fmaf(-2.0f, acc[mt][nt][reg], e2v);
                    unsigned int key = (__float_as_uint(d) & 0xFFFFFC00u) | kidx;
                    int s = mt*4+reg;
                    unsigned int o1 = k1[s], o2 = k2[s];
                    unsigned int nk2;
                    asm("v_med3_u32 %0, %1, %2, %3" : "=v"(nk2) : "v"(o1), "v"(o2), "v"(key));
                    k2[s] = nk2;                 // 2nd-smallest of {k1,k2,key}
                    k1[s] = min(o1, key);
                }
        }

        if (jt < 15 && tid < 64) e2s[nxt][tid] = e2r + DBIAS;
        __syncthreads();   // drains gll prefetch (vmcnt0), publishes buf nxt
    }

    // butterfly top-2 merge across the 16 col-lanes
#pragma unroll
    for (int off=1; off<16; off<<=1){
#pragma unroll
        for (int s=0;s<8;s++){
            unsigned int o1 = __shfl_xor(k1[s], off);
            unsigned int o2 = __shfl_xor(k2[s], off);
            unsigned int n1 = min(k1[s], o1);
            k2[s] = min( max(k1[s], o1), min(k2[s], o2) );
            k1[s] = n1;
        }
    }
    if (c == 0){
#pragma unroll
        for (int s=0;s<8;s++){
            int row = wm*32 + (s>>2)*16 + qq*4 + (s&3);
            mK[wn][row][0] = k1[s]; mK[wn][row][1] = k2[s];
        }
    }
    __syncthreads();

    if (tid < 64){
        int b = i0 + tid;
        unsigned int a1 = mK[0][tid][0], a2 = mK[0][tid][1];
        unsigned int c1 = mK[1][tid][0], c2 = mK[1][tid][1];
        unsigned int f1 = min(a1, c1);
        unsigned int f2 = min( max(a1, c1), min(a2, c2) );
        int ii1 = (int)(f1 & 0x3FFu);
        int ii2 = (int)(f2 & 0x3FFu);
        float d1q = __uint_as_float(f1 & 0xFFFFFC00u);
        float d2q = __uint_as_float(f2 & 0xFFFFFC00u);

        const float* eb = emb + (size_t)n*KC*SDIM;
        const float* zg = z + (size_t)b*LDIM + n*SDIM;
        if (d2q - d1q < 0.08f) {   // window covers quantization (0.031) + bf16 err
            double d1 = dist64d(eb + (size_t)ii1*SDIM, zg);
            double d2 = dist64d(eb + (size_t)ii2*SDIM, zg);
            if (d2 < d1 || (d2 == d1 && ii2 < ii1)) ii1 = ii2;
        }

        const float4* q4 = (const float4*)(eb + (size_t)ii1*SDIM);
        const float4* z4 = (const float4*)zg;
        float4* oq = (float4*)(out_q + (size_t)b*LDIM + n*SDIM);
        float cs = 0.f;
#pragma unroll
        for (int i=0;i<16;i++){
            float4 v = q4[i]; float4 zv = z4[i];
            oq[i] = v;
            float d0=v.x-zv.x, d1=v.y-zv.y, d2=v.z-zv.z, d3=v.w-zv.w;
            cs += d0*d0 + d1*d1 + d2*d2 + d3*d3;
        }
        out_idx[b*NCB + n] = (float)ii1;

        for (int off=32; off; off>>=1) cs += __shfl_down(cs, off);
        if (tid == 0) atomicAdd(&accs[0], cs);
    }
}

// ---------------------------------------------------------------------------
// K3: per-row L2 norms; write normalized FP8 (e4m3) copies + diag.
// Wave-per-row (4 rows/block), zero barriers, zero LDS, packed stores.
// ---------------------------------------------------------------------------
__global__ __launch_bounds__(256) void
k_norm(const float* __restrict__ z, const float* __restrict__ q,
       unsigned char* __restrict__ zn8, unsigned char* __restrict__ qn8,
       float* __restrict__ diag) {
    const int wid = threadIdx.x >> 6, lane = threadIdx.x & 63;
    const int b = blockIdx.x*4 + wid;
    const size_t base = (size_t)b*LDIM;
    const float4* z4 = (const float4*)(z + base + lane*8);
    const float4* q4 = (const float4*)(q + base + lane*8);
    float4 za = z4[0], zb = z4[1];
    float4 qa = q4[0], qb = q4[1];
    float sz = za.x*za.x + za.y*za.y + za.z*za.z + za.w*za.w
             + zb.x*zb.x + zb.y*zb.y + zb.z*zb.z + zb.w*zb.w;
    float sq = qa.x*qa.x + qa.y*qa.y + qa.z*qa.z + qa.w*qa.w
             + qb.x*qb.x + qb.y*qb.y + qb.z*qb.z + qb.w*qb.w;
    float sqz= qa.x*za.x + qa.y*za.y + qa.z*za.z + qa.w*za.w
             + qb.x*zb.x + qb.y*zb.y + qb.z*zb.z + qb.w*zb.w;
#pragma unroll
    for (int off=1; off<64; off<<=1){
        sz  += __shfl_xor(sz,  off);
        sq  += __shfl_xor(sq,  off);
        sqz += __shfl_xor(sqz, off);
    }
    float inz = 1.0f/fmaxf(sqrtf(sz), 1e-12f);
    float inq = 1.0f/fmaxf(sqrtf(sq), 1e-12f);
    if (lane == 0) diag[b] = sqz*inz*inq*INV_TAU;

    int z0 = __builtin_amdgcn_cvt_pk_fp8_f32(za.x*inz, za.y*inz, 0, false);
    z0     = __builtin_amdgcn_cvt_pk_fp8_f32(za.z*inz, za.w*inz, z0, true);
    int z1 = __builtin_amdgcn_cvt_pk_fp8_f32(zb.x*inz, zb.y*inz, 0, false);
    z1     = __builtin_amdgcn_cvt_pk_fp8_f32(zb.z*inz, zb.w*inz, z1, true);
    int q0 = __builtin_amdgcn_cvt_pk_fp8_f32(qa.x*inq, qa.y*inq, 0, false);
    q0     = __builtin_amdgcn_cvt_pk_fp8_f32(qa.z*inq, qa.w*inq, q0, true);
    int q1 = __builtin_amdgcn_cvt_pk_fp8_f32(qb.x*inq, qb.y*inq, 0, false);
    q1     = __builtin_amdgcn_cvt_pk_fp8_f32(qb.z*inq, qb.w*inq, q1, true);
    uint2 uz; uz.x = (unsigned)z0; uz.y = (unsigned)z1;
    uint2 uq; uq.x = (unsigned)q0; uq.y = (unsigned)q1;
    *(uint2*)(zn8 + base + lane*8) = uz;
    *(uint2*)(qn8 + base + lane*8) = uq;
}

// ---------------------------------------------------------------------------
// K4: logsumexp of logits = qn8 · zn8^T / TAU via MX-scaled fp8 MFMA
// 16x16x128 (scales=1.0). R6 build verbatim (best measured): 512-col
// chunks, grid (64,16) = 4 blocks/CU, XCD pin chnk=(bx&7)+8*(by&1),
// af[2][4] asm-pinned, nt-outer MFMA, gll dbuf B, 16 phases.
// ---------------------------------------------------------------------------
__global__ __launch_bounds__(256,4) void
k_logits(const unsigned char* __restrict__ qn8, const unsigned char* __restrict__ zn8,
         float* __restrict__ Spart) {
    __shared__ __align__(16) unsigned char Bs[2][32*512];
    const int tid  = threadIdx.x;
    // XCD pin: chnk from bx&7 (XCD id) + one by bit; row-tile from the rest.
    const int chnk = (blockIdx.x & 7) + ((blockIdx.y & 1) << 3);   // 0..15, 512 cols
    const int i0   = (((blockIdx.x >> 3) << 3) + (blockIdx.y >> 1)) * 128;
    const int wid  = tid >> 6, lane = tid & 63;
    const int wm = wid;                    // 4 m-groups of 32 rows
    const int c  = lane & 15, qq = lane >> 4;

    // gll lane geometry: 2 rows x 512B per wave-instr; source pre-swizzled
    const int brow  = lane >> 5;
    const int bchk0 = (lane & 31) * 16;

    auto stageB = [&](int buf, int j0){
#pragma unroll
        for (int s=0;s<4;s++){
            int r0  = wid*8 + s*2;
            int row = r0 + brow;
            gll16(zn8 + (size_t)(j0+row)*LDIM + (bchk0 ^ ((row&7)<<4)),
                  &Bs[buf][r0*512]);
        }
    };

    stageB(0, chnk*512);   // async; drained by the pre-loop barrier

    // ---- A resident in regs: 2 mt x 4 kc fragments (rows i0+wm*32+mt*16+c)
    intx8 af[2][4];
#pragma unroll
    for (int mt=0;mt<2;mt++){
        const unsigned char* ap = qn8 + (size_t)(i0 + wm*32 + mt*16 + c)*LDIM + qq*32;
#pragma unroll
        for (int kc=0;kc<4;kc++){
            union { intx8 v; uint4 h[2]; } u;
            u.h[0] = *(const uint4*)(ap + kc*128);
            u.h[1] = *(const uint4*)(ap + kc*128 + 16);
            af[mt][kc] = u.v;
        }
    }
    // pin af: opaque def makes rematerialization impossible (R4 lesson)
#pragma unroll
    for (int mt=0;mt<2;mt++)
#pragma unroll
        for (int kc=0;kc<4;kc++)
            asm volatile("" : "+v"(af[mt][kc]));

    float S[8];
#pragma unroll
    for (int i=0;i<8;i++) S[i] = 0.f;

    __syncthreads();        // drains stageB(0), publishes buf 0

    for (int jt=0;jt<16;jt++){
        const int cur = jt & 1;
        const int j0 = chnk*512 + jt*32;
        if (jt < 15) stageB(cur^1, j0 + 32);   // async prefetch next tile

        floatx4 acc[2][2];
#pragma unroll
        for (int mt=0;mt<2;mt++){
            acc[mt][0]=(floatx4){0.f,0.f,0.f,0.f};
            acc[mt][1]=(floatx4){0.f,0.f,0.f,0.f};
        }

#pragma unroll
        for (int kc=0;kc<4;kc++)
#pragma unroll
            for (int nt=0;nt<2;nt++){
                const int rb = nt*16 + c;          // tile row 0..31
                const unsigned char* p = &Bs[cur][rb*512];
                const int o = kc*128 + qq*32;
                const int x = (rb&7)<<4;
                union { intx8 v; uint4 h[2]; } u;
                u.h[0] = *(const uint4*)(p + (o ^ x));
                u.h[1] = *(const uint4*)(p + ((o + 16) ^ x));
                intx8 bfr = u.v;
#pragma unroll
                for (int mt=0;mt<2;mt++)
                    acc[mt][nt] = __builtin_amdgcn_mfma_scale_f32_16x16x128_f8f6f4(
                        af[mt][kc], bfr, acc[mt][nt],
                        0, 0,        // cbsz=FP8(e4m3), blgp=FP8(e4m3)
                        0, 127,      // scale_a opsel, scale_a (e8m0 1.0)
                        0, 127);     // scale_b opsel, scale_b
            }

        // S[row-slot] += sum_nt 2^((dot-1)*K2E)
#pragma unroll
        for (int mt=0;mt<2;mt++)
#pragma unroll
            for (int reg=0;reg<4;reg++){
                float e0 = exp2_fast(fmaf(acc[mt][0][reg], K2E, -K2E));
                float e1 = exp2_fast(fmaf(acc[mt][1][reg], K2E, -K2E));
                S[mt*4+reg] += e0 + e1;
            }
        __syncthreads();   // drains gll prefetch, publishes next buffer
    }

    // reduce over the 16 col-lanes (disjoint cols, same rows)
#pragma unroll
    for (int off=1; off<16; off<<=1)
#pragma unroll
        for (int s=0;s<8;s++) S[s] += __shfl_xor(S[s], off);

    if (c == 0){
        const int p = chnk;                    // 16 partial slots
#pragma unroll
        for (int mt=0;mt<2;mt++)
#pragma unroll
            for (int reg=0;reg<4;reg++){
                int row = i0 + wm*32 + mt*16 + qq*4 + reg;
                Spart[p*BATCH + row] = S[mt*4+reg];
            }
    }
}

// ---------------------------------------------------------------------------
// K5: combine 16 partials/row -> LSE - diag, reduce to accs[1]; the LAST
// block (device-scope counter accs[2]) also writes the two output scalars.
// ---------------------------------------------------------------------------
__global__ __launch_bounds__(256) void
k_finalize(const float* __restrict__ Spart, const float* __restrict__ diag,
           float* __restrict__ accs, float* __restrict__ out_s) {
    int r = blockIdx.x*256 + threadIdx.x;
    float Ssum = 0.f;
#pragma unroll
    for (int p=0;p<16;p++) Ssum += Spart[p*BATCH + r];
    float val = INV_TAU + logf(Ssum) - diag[r];
    for (int off=32; off; off>>=1) val += __shfl_down(val, off);
    if ((threadIdx.x & 63)==0) atomicAdd(&accs[1], val);
    __syncthreads();                       // drains this block's atomics
    if (threadIdx.x == 0){
        __threadfence();
        unsigned int old = __float_as_uint(atomicAdd(&accs[2], 1.0f));
        if (old == __float_as_uint(31.0f)) {   // 32nd (last) block
            __threadfence();
            float a0 = atomicAdd(&accs[0], 0.0f);
            float a1 = atomicAdd(&accs[1], 0.0f);
            out_s[0] = 2.0f*a0 / (float)((size_t)BATCH*LDIM);   // commit+embed
            out_s[1] = a1 / (float)BATCH;                       // contrastive
        }
    }
}

// ---------------------------------------------------------------------------
extern "C" void kernel_launch(void* const* d_in, const int* in_sizes, int n_in,
                              void* d_out, int out_size, void* d_ws, size_t ws_size,
                              hipStream_t stream) {
    const float* z   = (const float*)d_in[0];   // (B, L)
    const float* emb = (const float*)d_in[1];   // (NC, K, SD)
    float* out = (float*)d_out;
    float* out_q       = out;                   // B*L = 4194304
    float* out_scalars = out + 4194304;         // [commit, contrastive]
    float* out_idx     = out + 4194306;         // B*NC as float

    // ws layout (float offsets); ~11 MB total
    float* wsf   = (float*)d_ws;
    float* e2    = wsf;                         // 8192
    float* accs  = wsf + 8192;                  // [commit, contrastive, counter]
    float* diag  = wsf + 8704;                  // 8192
    float* Spart = wsf + 16896;                 // 16 slots used (32 reserved)
    unsigned char* qn8 = (unsigned char*)(Spart + 32*BATCH);   // B*L fp8 (4 MB)
    unsigned char* zn8 = qn8 + (size_t)BATCH*LDIM;             // B*L fp8 (4 MB)
    unsigned short* eh = (unsigned short*)(zn8 + (size_t)BATCH*LDIM); // NC*K*SD bf16
    unsigned short* el = eh + (size_t)NCB*KC*SDIM;             // NC*K*SD bf16

    k_pre    <<<256,         256, 0, stream>>>(emb, e2, eh, el, accs);
    k_argmin <<<dim3(128,8), 256, 0, stream>>>(eh, el, e2, z, emb,
                                               out_q, out_idx, accs);
    k_norm   <<<2048,        256, 0, stream>>>(z, out_q, zn8, qn8, diag);
    k_logits <<<dim3(64,16), 256, 0, stream>>>(qn8, zn8, Spart);
    k_finalize<<<32,         256, 0, stream>>>(Spart, diag, accs, out_scalars);
}

// Round 10
// 167.224 us; speedup vs baseline: 1.0210x; 1.0210x over previous
//
#include <hip/hip_runtime.h>
#include <cstdint>
#include <cstddef>

// Problem constants
#define NCB   8
#define KC    1024
#define SDIM  64
#define LDIM  512          // NCB*SDIM
#define BATCH 8192
#define INV_TAU (1.0f/0.07f)
#define K2E  20.60992915555662f   // log2(e)/TAU
#define DBIAS 256.0f           // dist bias: dist+256 in [174,466) -> positive, 2 binades

typedef __bf16 bf16_t;
typedef bf16_t bf16x8 __attribute__((ext_vector_type(8)));
typedef float  floatx4 __attribute__((ext_vector_type(4)));
typedef int    intx8  __attribute__((ext_vector_type(8)));
typedef unsigned int u32;

__device__ __forceinline__ unsigned short f2bf(float f) {
    union { float f; unsigned int u; } c; c.f = f;
    unsigned int u = c.u;
    u += 0x7fffu + ((u >> 16) & 1u);   // round-to-nearest-even
    return (unsigned short)(u >> 16);
}
__device__ __forceinline__ float bf2f(unsigned short h) {
    union { unsigned int u; float f; } c; c.u = ((unsigned int)h) << 16;
    return c.f;
}
__device__ __forceinline__ float exp2_fast(float x) {
    float r; asm("v_exp_f32 %0, %1" : "=v"(r) : "v"(x)); return r;
}
// async global->LDS DMA, 16B/lane. LDS dest = wave-uniform base + lane*16 (linear).
__device__ __forceinline__ void gll16(const void* g, void* l) {
    __builtin_amdgcn_global_load_lds(
        (const __attribute__((address_space(1))) u32*)g,
        (__attribute__((address_space(3))) u32*)l,
        16, 0, 0);
}

// ---------------------------------------------------------------------------
// K0: embeddings: e2 + bf16 hi/lo split + zero accs. 256 blocks, 8 lanes/row.
// ---------------------------------------------------------------------------
__global__ __launch_bounds__(256) void
k_pre(const float* __restrict__ emb, float* __restrict__ e2,
      unsigned short* __restrict__ eh, unsigned short* __restrict__ el,
      float* __restrict__ accs) {
    int gid = blockIdx.x * 256 + threadIdx.x;   // 0..65535
    int row = gid >> 3, g = gid & 7;            // row 0..8191, 8 floats/lane
    const float4* e4 = (const float4*)(emb + (size_t)row*SDIM + g*8);
    float4 a = e4[0], b = e4[1];
    union { ushort4 u4[2]; uint4 v; } H, L;
    H.u4[0].x=f2bf(a.x); L.u4[0].x=f2bf(a.x-bf2f(H.u4[0].x));
    H.u4[0].y=f2bf(a.y); L.u4[0].y=f2bf(a.y-bf2f(H.u4[0].y));
    H.u4[0].z=f2bf(a.z); L.u4[0].z=f2bf(a.z-bf2f(H.u4[0].z));
    H.u4[0].w=f2bf(a.w); L.u4[0].w=f2bf(a.w-bf2f(H.u4[0].w));
    H.u4[1].x=f2bf(b.x); L.u4[1].x=f2bf(b.x-bf2f(H.u4[1].x));
    H.u4[1].y=f2bf(b.y); L.u4[1].y=f2bf(b.y-bf2f(H.u4[1].y));
    H.u4[1].z=f2bf(b.z); L.u4[1].z=f2bf(b.z-bf2f(H.u4[1].z));
    H.u4[1].w=f2bf(b.w); L.u4[1].w=f2bf(b.w-bf2f(H.u4[1].w));
    *(uint4*)(eh + (size_t)row*SDIM + g*8) = H.v;
    *(uint4*)(el + (size_t)row*SDIM + g*8) = L.v;
    float s = a.x*a.x + a.y*a.y + a.z*a.z + a.w*a.w
            + b.x*b.x + b.y*b.y + b.z*b.z + b.w*b.w;
    s += __shfl_xor(s, 1); s += __shfl_xor(s, 2); s += __shfl_xor(s, 4);
    if (g == 0) e2[row] = s;
    if (gid == 0){ accs[0]=0.f; accs[1]=0.f; accs[2]=0.f; }
}

// fp64 "relative distance" e2 - 2*z.e (z2 cancels in argmin ordering)
__device__ __forceinline__ double dist64d(const float* __restrict__ e,
                                          const float* __restrict__ zg) {
    double se=0.0, sz=0.0;
#pragma unroll 8
    for (int i=0;i<64;i++){ double ev=(double)e[i];
        se = fma(ev,ev,se); sz = fma(ev,(double)zg[i],sz); }
    return se - 2.0*sz;
}

// ---------------------------------------------------------------------------
// K2: MFMA argmin. R23: ONE 8-wave block per CU (m201 regime).
// R9 post-mortem: B-staging is per-block (64 codes x 16 phases regardless
// of rows) — halving blocks' rows DOUBLED total staging. So go the other
// way: 256 rows x 512 threads, grid (32,8) = 1 block/CU. Each staged tile
// feeds 2x MFMA; phase-instances across grid halve. With no partner block
// to hide barrier convergence this needs the counted-vmcnt pipeline:
// 3-buffer ring, 2-deep prefetch, vmcnt(2)+raw s_barrier (the T3/T4
// prerequisite — 8 waves of role diversity inside one barrier scope — now
// exists; R8's null was at 2 blocks/CU where the partner gave slack).
// e2 preloaded once -> glls are the only in-loop VMEM (exact count).
// LDS: A 64K + B-ring 48K + e2 4K + mK 4K ~= 120 KB. XCD pin n=bx&7.
// ---------------------------------------------------------------------------
__global__ __launch_bounds__(512,1) void
k_argmin(const unsigned short* __restrict__ eh, const unsigned short* __restrict__ el,
         const float* __restrict__ e2, const float* __restrict__ z,
         const float* __restrict__ emb, float* __restrict__ out_q,
         float* __restrict__ out_idx, float* __restrict__ accs) {
    __shared__ __align__(16) unsigned short Ah[256*64], Al[256*64];     // 64 KB
    __shared__ __align__(16) unsigned short Bh[3][64*64], Bl[3][64*64]; // 48 KB
    __shared__ float e2s[1024];                                         // 4 KB
    __shared__ unsigned int mK[2][256][2];                              // 4 KB

    const int tid = threadIdx.x;
    // XCD pin: n = bx&7 (== XCD id, gridDim.x=32 ≡ 0 mod 8); row-tile rest.
    const int n   = blockIdx.x & 7;
    const int i0  = ((blockIdx.x >> 3) | (blockIdx.y << 2)) * 256;  // 0..31 tiles
    const int wid = tid >> 6, lane = tid & 63;
    const int wm = wid & 3, wn = wid >> 2;    // 4 m-groups x 2 n-groups
    const int c  = lane & 15, qq = lane >> 4;

    const unsigned char* ehb = (const unsigned char*)(eh + (size_t)n*KC*SDIM);
    const unsigned char* elb = (const unsigned char*)(el + (size_t)n*KC*SDIM);
    const float* e2n = e2 + n*KC;

    // gll lane geometry: 8 rows x 128B per wave-instr; source pre-swizzled
    const int brow = lane >> 3;                       // row-in-8
    const int bchk = ((lane & 7)*16) ^ (brow << 4);   // swizzled byte in row

    auto stageB = [&](int buf, int j0){               // 8 waves x 8 rows = 64
        int r0 = wid*8;
        size_t go = (size_t)(j0 + r0 + brow)*128 + bchk;
        gll16(ehb + go, &Bh[buf][r0*64]);
        gll16(elb + go, &Bl[buf][r0*64]);
    };

    stageB(0, 0);          // tiles 0,1; drained by the full pre-loop barrier
    stageB(1, 64);

    // stage A (resident): read z fp32, split hi/lo in-kernel, swizzled store
#pragma unroll
    for (int s=0;s<8;s++){
        int seg = tid + s*512;           // 4096 segs; 16 float4-segs per row
        int r = seg >> 4, sg = seg & 15;
        float4 v = *(const float4*)(z + (size_t)(i0+r)*LDIM + n*SDIM + sg*4);
        ushort4 h, l;
        h.x=f2bf(v.x); l.x=f2bf(v.x-bf2f(h.x));
        h.y=f2bf(v.y); l.y=f2bf(v.y-bf2f(h.y));
        h.z=f2bf(v.z); l.z=f2bf(v.z-bf2f(h.z));
        h.w=f2bf(v.w); l.w=f2bf(v.w-bf2f(h.w));
        int off = r*64 + ((sg*4) ^ ((r&7)<<3));   // shorts; == byte XOR (r&7)<<4
        *(ushort4*)(&Ah[off]) = h;
        *(ushort4*)(&Al[off]) = l;
    }
    // e2 preloaded ONCE (keeps in-loop VMEM = glls only)
    e2s[tid]       = e2n[tid]       + DBIAS;
    e2s[tid + 512] = e2n[tid + 512] + DBIAS;

    unsigned int k1[16], k2[16];
#pragma unroll
    for (int j=0;j<16;j++){ k1[j]=0xFFFFFFFFu; k2[j]=0xFFFFFFFFu; }

    __syncthreads();       // full drain: A, e2s, tiles 0,1 all visible

    for (int jt=0; jt<16; jt++){
        const int cur = jt % 3;
        const int j0 = jt*64;
        if (jt < 14) stageB((jt+2)%3, j0 + 128);   // 2-deep async prefetch

        floatx4 acc[4][2];
#pragma unroll
        for (int mt=0;mt<4;mt++){
            acc[mt][0]=(floatx4){0.f,0.f,0.f,0.f};
            acc[mt][1]=(floatx4){0.f,0.f,0.f,0.f};
        }

#pragma unroll
        for (int t=0;t<2;t++){
            const int axo = (t*32 + qq*8) ^ ((c&7)<<3);   // shorts
            bf16x8 ah[4], alo[4], bh[2], bl[2];
#pragma unroll
            for (int mt=0;mt<4;mt++){
                int ro = (wm*64 + mt*16 + c)*64 + axo;
                ah[mt]  = *(const bf16x8*)(&Ah[ro]);
                alo[mt] = *(const bf16x8*)(&Al[ro]);
            }
#pragma unroll
            for (int nt=0;nt<2;nt++){
                int ro = (wn*32 + nt*16 + c)*64 + axo;
                bh[nt] = *(const bf16x8*)(&Bh[cur][ro]);
                bl[nt] = *(const bf16x8*)(&Bl[cur][ro]);
            }
#pragma unroll
            for (int mt=0;mt<4;mt++)
#pragma unroll
                for (int nt=0;nt<2;nt++){
                    acc[mt][nt] = __builtin_amdgcn_mfma_f32_16x16x32_bf16(ah[mt],  bh[nt], acc[mt][nt], 0,0,0);
                    acc[mt][nt] = __builtin_amdgcn_mfma_f32_16x16x32_bf16(ah[mt],  bl[nt], acc[mt][nt], 0,0,0);
                    acc[mt][nt] = __builtin_amdgcn_mfma_f32_16x16x32_bf16(alo[mt], bh[nt], acc[mt][nt], 0,0,0);
                }
        }

        // biased dist -> packed key -> branchless top-2 (min + med3)
#pragma unroll
        for (int nt=0;nt<2;nt++){
            const int colb = wn*32 + nt*16 + c;
            float e2v = e2s[j0 + colb];
            unsigned int kidx = (unsigned int)(j0 + colb);
#pragma unroll
            for (int mt=0;mt<4;mt++)
#pragma unroll
                for (int reg=0;reg<4;reg++){
                    float d = fmaf(-2.0f, acc[mt][nt][reg], e2v);
                    unsigned int key = (__float_as_uint(d) & 0xFFFFFC00u) | kidx;
                    int s = mt*4+reg;
                    unsigned int o1 = k1[s], o2 = k2[s];
                    unsigned int nk2;
                    asm("v_med3_u32 %0, %1, %2, %3" : "=v"(nk2) : "v"(o1), "v"(o2), "v"(key));
                    k2[s] = nk2;                 // 2nd-smallest of {k1,k2,key}
                    k1[s] = min(o1, key);
                }
        }

        // counted wait: tile jt+1 done; tile jt+2's 2 glls stay in flight
        if (jt < 14) { asm volatile("s_waitcnt vmcnt(2)" ::: "memory"); }
        else         { asm volatile("s_waitcnt vmcnt(0)" ::: "memory"); }
        __builtin_amdgcn_sched_barrier(0);
        __builtin_amdgcn_s_barrier();
        __builtin_amdgcn_sched_barrier(0);
    }

    // butterfly top-2 merge across the 16 col-lanes
#pragma unroll
    for (int off=1; off<16; off<<=1){
#pragma unroll
        for (int s=0;s<16;s++){
            unsigned int o1 = __shfl_xor(k1[s], off);
            unsigned int o2 = __shfl_xor(k2[s], off);
            unsigned int n1 = min(k1[s], o1);
            k2[s] = min( max(k1[s], o1), min(k2[s], o2) );
            k1[s] = n1;
        }
    }
    if (c == 0){
#pragma unroll
        for (int s=0;s<16;s++){
            int row = wm*64 + (s>>2)*16 + qq*4 + (s&3);
            mK[wn][row][0] = k1[s]; mK[wn][row][1] = k2[s];
        }
    }
    __syncthreads();

    if (tid < 256){
        int b = i0 + tid;
        unsigned int a1 = mK[0][tid][0], a2 = mK[0][tid][1];
        unsigned int c1 = mK[1][tid][0], c2 = mK[1][tid][1];
        unsigned int f1 = min(a1, c1);
        unsigned int f2 = min( max(a1, c1), min(a2, c2) );
        int ii1 = (int)(f1 & 0x3FFu);
        int ii2 = (int)(f2 & 0x3FFu);
        float d1q = __uint_as_float(f1 & 0xFFFFFC00u);
        float d2q = __uint_as_float(f2 & 0xFFFFFC00u);

        const float* eb = emb + (size_t)n*KC*SDIM;
        const float* zg = z + (size_t)b*LDIM + n*SDIM;
        if (d2q - d1q < 0.08f) {   // window covers quantization (0.031) + bf16 err
            double d1 = dist64d(eb + (size_t)ii1*SDIM, zg);
            double d2 = dist64d(eb + (size_t)ii2*SDIM, zg);
            if (d2 < d1 || (d2 == d1 && ii2 < ii1)) ii1 = ii2;
        }

        const float4* q4 = (const float4*)(eb + (size_t)ii1*SDIM);
        const float4* z4 = (const float4*)zg;
        float4* oq = (float4*)(out_q + (size_t)b*LDIM + n*SDIM);
        float cs = 0.f;
#pragma unroll
        for (int i=0;i<16;i++){
            float4 v = q4[i]; float4 zv = z4[i];
            oq[i] = v;
            float d0=v.x-zv.x, d1=v.y-zv.y, d2=v.z-zv.z, d3=v.w-zv.w;
            cs += d0*d0 + d1*d1 + d2*d2 + d3*d3;
        }
        out_idx[b*NCB + n] = (float)ii1;

        for (int off=32; off; off>>=1) cs += __shfl_down(cs, off);
        if ((tid & 63)==0) atomicAdd(&accs[0], cs);
    }
}

// ---------------------------------------------------------------------------
// K3: per-row L2 norms; write normalized FP8 (e4m3) copies + diag.
// Wave-per-row (4 rows/block), zero barriers, zero LDS, packed stores.
// ---------------------------------------------------------------------------
__global__ __launch_bounds__(256) void
k_norm(const float* __restrict__ z, const float* __restrict__ q,
       unsigned char* __restrict__ zn8, unsigned char* __restrict__ qn8,
       float* __restrict__ diag) {
    const int wid = threadIdx.x >> 6, lane = threadIdx.x & 63;
    const int b = blockIdx.x*4 + wid;
    const size_t base = (size_t)b*LDIM;
    const float4* z4 = (const float4*)(z + base + lane*8);
    const float4* q4 = (const float4*)(q + base + lane*8);
    float4 za = z4[0], zb = z4[1];
    float4 qa = q4[0], qb = q4[1];
    float sz = za.x*za.x + za.y*za.y + za.z*za.z + za.w*za.w
             + zb.x*zb.x + zb.y*zb.y + zb.z*zb.z + zb.w*zb.w;
    float sq = qa.x*qa.x + qa.y*qa.y + qa.z*qa.z + qa.w*qa.w
             + qb.x*qb.x + qb.y*qb.y + qb.z*qb.z + qb.w*qb.w;
    float sqz= qa.x*za.x + qa.y*za.y + qa.z*za.z + qa.w*za.w
             + qb.x*zb.x + qb.y*zb.y + qb.z*zb.z + qb.w*zb.w;
#pragma unroll
    for (int off=1; off<64; off<<=1){
        sz  += __shfl_xor(sz,  off);
        sq  += __shfl_xor(sq,  off);
        sqz += __shfl_xor(sqz, off);
    }
    float inz = 1.0f/fmaxf(sqrtf(sz), 1e-12f);
    float inq = 1.0f/fmaxf(sqrtf(sq), 1e-12f);
    if (lane == 0) diag[b] = sqz*inz*inq*INV_TAU;

    int z0 = __builtin_amdgcn_cvt_pk_fp8_f32(za.x*inz, za.y*inz, 0, false);
    z0     = __builtin_amdgcn_cvt_pk_fp8_f32(za.z*inz, za.w*inz, z0, true);
    int z1 = __builtin_amdgcn_cvt_pk_fp8_f32(zb.x*inz, zb.y*inz, 0, false);
    z1     = __builtin_amdgcn_cvt_pk_fp8_f32(zb.z*inz, zb.w*inz, z1, true);
    int q0 = __builtin_amdgcn_cvt_pk_fp8_f32(qa.x*inq, qa.y*inq, 0, false);
    q0     = __builtin_amdgcn_cvt_pk_fp8_f32(qa.z*inq, qa.w*inq, q0, true);
    int q1 = __builtin_amdgcn_cvt_pk_fp8_f32(qb.x*inq, qb.y*inq, 0, false);
    q1     = __builtin_amdgcn_cvt_pk_fp8_f32(qb.z*inq, qb.w*inq, q1, true);
    uint2 uz; uz.x = (unsigned)z0; uz.y = (unsigned)z1;
    uint2 uq; uq.x = (unsigned)q0; uq.y = (unsigned)q1;
    *(uint2*)(zn8 + base + lane*8) = uz;
    *(uint2*)(qn8 + base + lane*8) = uq;
}

// ---------------------------------------------------------------------------
// K4: logsumexp of logits = qn8 · zn8^T / TAU via MX-scaled fp8 MFMA
// 16x16x128 (scales=1.0). R6 build verbatim (best measured): 512-col
// chunks, grid (64,16) = 4 blocks/CU, XCD pin chnk=(bx&7)+8*(by&1),
// af[2][4] asm-pinned, nt-outer MFMA, gll dbuf B, 16 phases.
// ---------------------------------------------------------------------------
__global__ __launch_bounds__(256,4) void
k_logits(const unsigned char* __restrict__ qn8, const unsigned char* __restrict__ zn8,
         float* __restrict__ Spart) {
    __shared__ __align__(16) unsigned char Bs[2][32*512];
    const int tid  = threadIdx.x;
    // XCD pin: chnk from bx&7 (XCD id) + one by bit; row-tile from the rest.
    const int chnk = (blockIdx.x & 7) + ((blockIdx.y & 1) << 3);   // 0..15, 512 cols
    const int i0   = (((blockIdx.x >> 3) << 3) + (blockIdx.y >> 1)) * 128;
    const int wid  = tid >> 6, lane = tid & 63;
    const int wm = wid;                    // 4 m-groups of 32 rows
    const int c  = lane & 15, qq = lane >> 4;

    // gll lane geometry: 2 rows x 512B per wave-instr; source pre-swizzled
    const int brow  = lane >> 5;
    const int bchk0 = (lane & 31) * 16;

    auto stageB = [&](int buf, int j0){
#pragma unroll
        for (int s=0;s<4;s++){
            int r0  = wid*8 + s*2;
            int row = r0 + brow;
            gll16(zn8 + (size_t)(j0+row)*LDIM + (bchk0 ^ ((row&7)<<4)),
                  &Bs[buf][r0*512]);
        }
    };

    stageB(0, chnk*512);   // async; drained by the pre-loop barrier

    // ---- A resident in regs: 2 mt x 4 kc fragments (rows i0+wm*32+mt*16+c)
    intx8 af[2][4];
#pragma unroll
    for (int mt=0;mt<2;mt++){
        const unsigned char* ap = qn8 + (size_t)(i0 + wm*32 + mt*16 + c)*LDIM + qq*32;
#pragma unroll
        for (int kc=0;kc<4;kc++){
            union { intx8 v; uint4 h[2]; } u;
            u.h[0] = *(const uint4*)(ap + kc*128);
            u.h[1] = *(const uint4*)(ap + kc*128 + 16);
            af[mt][kc] = u.v;
        }
    }
    // pin af: opaque def makes rematerialization impossible (R4 lesson)
#pragma unroll
    for (int mt=0;mt<2;mt++)
#pragma unroll
        for (int kc=0;kc<4;kc++)
            asm volatile("" : "+v"(af[mt][kc]));

    float S[8];
#pragma unroll
    for (int i=0;i<8;i++) S[i] = 0.f;

    __syncthreads();        // drains stageB(0), publishes buf 0

    for (int jt=0;jt<16;jt++){
        const int cur = jt & 1;
        const int j0 = chnk*512 + jt*32;
        if (jt < 15) stageB(cur^1, j0 + 32);   // async prefetch next tile

        floatx4 acc[2][2];
#pragma unroll
        for (int mt=0;mt<2;mt++){
            acc[mt][0]=(floatx4){0.f,0.f,0.f,0.f};
            acc[mt][1]=(floatx4){0.f,0.f,0.f,0.f};
        }

#pragma unroll
        for (int kc=0;kc<4;kc++)
#pragma unroll
            for (int nt=0;nt<2;nt++){
                const int rb = nt*16 + c;          // tile row 0..31
                const unsigned char* p = &Bs[cur][rb*512];
                const int o = kc*128 + qq*32;
                const int x = (rb&7)<<4;
                union { intx8 v; uint4 h[2]; } u;
                u.h[0] = *(const uint4*)(p + (o ^ x));
                u.h[1] = *(const uint4*)(p + ((o + 16) ^ x));
                intx8 bfr = u.v;
#pragma unroll
                for (int mt=0;mt<2;mt++)
                    acc[mt][nt] = __builtin_amdgcn_mfma_scale_f32_16x16x128_f8f6f4(
                        af[mt][kc], bfr, acc[mt][nt],
                        0, 0,        // cbsz=FP8(e4m3), blgp=FP8(e4m3)
                        0, 127,      // scale_a opsel, scale_a (e8m0 1.0)
                        0, 127);     // scale_b opsel, scale_b
            }

        // S[row-slot] += sum_nt 2^((dot-1)*K2E)
#pragma unroll
        for (int mt=0;mt<2;mt++)
#pragma unroll
            for (int reg=0;reg<4;reg++){
                float e0 = exp2_fast(fmaf(acc[mt][0][reg], K2E, -K2E));
                float e1 = exp2_fast(fmaf(acc[mt][1][reg], K2E, -K2E));
                S[mt*4+reg] += e0 + e1;
            }
        __syncthreads();   // drains gll prefetch, publishes next buffer
    }

    // reduce over the 16 col-lanes (disjoint cols, same rows)
#pragma unroll
    for (int off=1; off<16; off<<=1)
#pragma unroll
        for (int s=0;s<8;s++) S[s] += __shfl_xor(S[s], off);

    if (c == 0){
        const int p = chnk;                    // 16 partial slots
#pragma unroll
        for (int mt=0;mt<2;mt++)
#pragma unroll
            for (int reg=0;reg<4;reg++){
                int row = i0 + wm*32 + mt*16 + qq*4 + reg;
                Spart[p*BATCH + row] = S[mt*4+reg];
            }
    }
}

// ---------------------------------------------------------------------------
// K5: combine 16 partials/row -> LSE - diag, reduce to accs[1]; the LAST
// block (device-scope counter accs[2]) also writes the two output scalars.
// ---------------------------------------------------------------------------
__global__ __launch_bounds__(256) void
k_finalize(const float* __restrict__ Spart, const float* __restrict__ diag,
           float* __restrict__ accs, float* __restrict__ out_s) {
    int r = blockIdx.x*256 + threadIdx.x;
    float Ssum = 0.f;
#pragma unroll
    for (int p=0;p<16;p++) Ssum += Spart[p*BATCH + r];
    float val = INV_TAU + logf(Ssum) - diag[r];
    for (int off=32; off; off>>=1) val += __shfl_down(val, off);
    if ((threadIdx.x & 63)==0) atomicAdd(&accs[1], val);
    __syncthreads();                       // drains this block's atomics
    if (threadIdx.x == 0){
        __threadfence();
        unsigned int old = __float_as_uint(atomicAdd(&accs[2], 1.0f));
        if (old == __float_as_uint(31.0f)) {   // 32nd (last) block
            __threadfence();
            float a0 = atomicAdd(&accs[0], 0.0f);
            float a1 = atomicAdd(&accs[1], 0.0f);
            out_s[0] = 2.0f*a0 / (float)((size_t)BATCH*LDIM);   // commit+embed
            out_s[1] = a1 / (float)BATCH;                       // contrastive
        }
    }
}

// ---------------------------------------------------------------------------
extern "C" void kernel_launch(void* const* d_in, const int* in_sizes, int n_in,
                              void* d_out, int out_size, void* d_ws, size_t ws_size,
                              hipStream_t stream) {
    const float* z   = (const float*)d_in[0];   // (B, L)
    const float* emb = (const float*)d_in[1];   // (NC, K, SD)
    float* out = (float*)d_out;
    float* out_q       = out;                   // B*L = 4194304
    float* out_scalars = out + 4194304;         // [commit, contrastive]
    float* out_idx     = out + 4194306;         // B*NC as float

    // ws layout (float offsets); ~11 MB total
    float* wsf   = (float*)d_ws;
    float* e2    = wsf;                         // 8192
    float* accs  = wsf + 8192;                  // [commit, contrastive, counter]
    float* diag  = wsf + 8704;                  // 8192
    float* Spart = wsf + 16896;                 // 16 slots used (32 reserved)
    unsigned char* qn8 = (unsigned char*)(Spart + 32*BATCH);   // B*L fp8 (4 MB)
    unsigned char* zn8 = qn8 + (size_t)BATCH*LDIM;             // B*L fp8 (4 MB)
    unsigned short* eh = (unsigned short*)(zn8 + (size_t)BATCH*LDIM); // NC*K*SD bf16
    unsigned short* el = eh + (size_t)NCB*KC*SDIM;             // NC*K*SD bf16

    k_pre    <<<256,         256, 0, stream>>>(emb, e2, eh, el, accs);
    k_argmin <<<dim3(32,8),  512, 0, stream>>>(eh, el, e2, z, emb,
                                               out_q, out_idx, accs);
    k_norm   <<<2048,        256, 0, stream>>>(z, out_q, zn8, qn8, diag);
    k_logits <<<dim3(64,16), 256, 0, stream>>>(qn8, zn8, Spart);
    k_finalize<<<32,         256, 0, stream>>>(Spart, diag, accs, out_scalars);
}

// Round 11
// 161.871 us; speedup vs baseline: 1.0548x; 1.0331x over previous
//
#include <hip/hip_runtime.h>
#include <cstdint>
#include <cstddef>

// Problem constants
#define NCB   8
#define KC    1024
#define SDIM  64
#define LDIM  512          // NCB*SDIM
#define BATCH 8192
#define INV_TAU (1.0f/0.07f)
#define K2E  20.60992915555662f   // log2(e)/TAU
#define DBIAS 256.0f           // dist bias: dist+256 in [174,466) -> positive, 2 binades

typedef __bf16 bf16_t;
typedef bf16_t bf16x8 __attribute__((ext_vector_type(8)));
typedef float  floatx4 __attribute__((ext_vector_type(4)));
typedef int    intx8  __attribute__((ext_vector_type(8)));
typedef unsigned int u32;

__device__ __forceinline__ unsigned short f2bf(float f) {
    union { float f; unsigned int u; } c; c.f = f;
    unsigned int u = c.u;
    u += 0x7fffu + ((u >> 16) & 1u);   // round-to-nearest-even
    return (unsigned short)(u >> 16);
}
__device__ __forceinline__ float bf2f(unsigned short h) {
    union { unsigned int u; float f; } c; c.u = ((unsigned int)h) << 16;
    return c.f;
}
__device__ __forceinline__ float exp2_fast(float x) {
    float r; asm("v_exp_f32 %0, %1" : "=v"(r) : "v"(x)); return r;
}
// async global->LDS DMA, 16B/lane. LDS dest = wave-uniform base + lane*16 (linear).
__device__ __forceinline__ void gll16(const void* g, void* l) {
    __builtin_amdgcn_global_load_lds(
        (const __attribute__((address_space(1))) u32*)g,
        (__attribute__((address_space(3))) u32*)l,
        16, 0, 0);
}

// ---------------------------------------------------------------------------
// K0: embeddings: e2 + bf16 hi/lo split + zero accs. 256 blocks, 8 lanes/row.
// ---------------------------------------------------------------------------
__global__ __launch_bounds__(256) void
k_pre(const float* __restrict__ emb, float* __restrict__ e2,
      unsigned short* __restrict__ eh, unsigned short* __restrict__ el,
      float* __restrict__ accs) {
    int gid = blockIdx.x * 256 + threadIdx.x;   // 0..65535
    int row = gid >> 3, g = gid & 7;            // row 0..8191, 8 floats/lane
    const float4* e4 = (const float4*)(emb + (size_t)row*SDIM + g*8);
    float4 a = e4[0], b = e4[1];
    union { ushort4 u4[2]; uint4 v; } H, L;
    H.u4[0].x=f2bf(a.x); L.u4[0].x=f2bf(a.x-bf2f(H.u4[0].x));
    H.u4[0].y=f2bf(a.y); L.u4[0].y=f2bf(a.y-bf2f(H.u4[0].y));
    H.u4[0].z=f2bf(a.z); L.u4[0].z=f2bf(a.z-bf2f(H.u4[0].z));
    H.u4[0].w=f2bf(a.w); L.u4[0].w=f2bf(a.w-bf2f(H.u4[0].w));
    H.u4[1].x=f2bf(b.x); L.u4[1].x=f2bf(b.x-bf2f(H.u4[1].x));
    H.u4[1].y=f2bf(b.y); L.u4[1].y=f2bf(b.y-bf2f(H.u4[1].y));
    H.u4[1].z=f2bf(b.z); L.u4[1].z=f2bf(b.z-bf2f(H.u4[1].z));
    H.u4[1].w=f2bf(b.w); L.u4[1].w=f2bf(b.w-bf2f(H.u4[1].w));
    *(uint4*)(eh + (size_t)row*SDIM + g*8) = H.v;
    *(uint4*)(el + (size_t)row*SDIM + g*8) = L.v;
    float s = a.x*a.x + a.y*a.y + a.z*a.z + a.w*a.w
            + b.x*b.x + b.y*b.y + b.z*b.z + b.w*b.w;
    s += __shfl_xor(s, 1); s += __shfl_xor(s, 2); s += __shfl_xor(s, 4);
    if (g == 0) e2[row] = s;
    if (gid == 0){ accs[0]=0.f; accs[1]=0.f; accs[2]=0.f; }
}

// fp64 "relative distance" e2 - 2*z.e (z2 cancels in argmin ordering)
__device__ __forceinline__ double dist64d(const float* __restrict__ e,
                                          const float* __restrict__ zg) {
    double se=0.0, sz=0.0;
#pragma unroll 8
    for (int i=0;i<64;i++){ double ev=(double)e[i];
        se = fma(ev,ev,se); sz = fma(ev,(double)zg[i],sz); }
    return se - 2.0*sz;
}

// ---------------------------------------------------------------------------
// K2: MFMA argmin. R24: BARRIER-FREE main loop (code-partitioned waves).
// R5/R8/R9/R10 dataset: cost ~= barrier-CONVERGENCE x phase-instances;
// counted-vmcnt == drain (R8), occupancy moves fail (R9/R10). So delete
// the in-loop barrier: block = 64 rows x 4 waves; wave w privately scans
// codes [256w,256w+256) in 8x32-code tiles with B fragments loaded
// DIRECTLY global->registers (1-deep reg double-buffer, fully unrolled
// loop => static indices, rule #20; 16 code-rows x 64B contiguous reads,
// XCD-L2-resident). A in LDS (16 KB, swizzled, staged once). Barriers:
// ONE after A-stage + ONE before the 4-way top-2 merge. R3's direct-load
// failure addressed: explicit prefetch + VGPR ~190 <= 256 cap (2 w/SIMD).
// LDS 22 KB. Grid (128,8), XCD pin n=bx&7. Epilogue serial (R7 lesson).
// ---------------------------------------------------------------------------
__global__ __launch_bounds__(256,2) void
k_argmin(const unsigned short* __restrict__ eh, const unsigned short* __restrict__ el,
         const float* __restrict__ e2, const float* __restrict__ z,
         const float* __restrict__ emb, float* __restrict__ out_q,
         float* __restrict__ out_idx, float* __restrict__ accs) {
    __shared__ __align__(16) unsigned short Ah[64*64], Al[64*64];   // 16 KB
    __shared__ float e2s[1024];                                     // 4 KB
    __shared__ unsigned int mK[4][64][2];                           // 2 KB

    const int tid = threadIdx.x;
    // XCD pin: n = bx&7 (== XCD id); row-tile from remaining bits.
    const int n   = blockIdx.x & 7;
    const int i0  = ((blockIdx.x >> 3) | (blockIdx.y << 4)) * 64;   // 0..127 tiles
    const int wid = tid >> 6, lane = tid & 63;
    const int c  = lane & 15, qq = lane >> 4;

    // stage A (resident): read z fp32, split hi/lo in-kernel, swizzled store
#pragma unroll
    for (int s=0;s<4;s++){
        int seg = tid + s*256;           // 1024 segs; 16 float4-segs per row
        int r = seg >> 4, sg = seg & 15;
        float4 v = *(const float4*)(z + (size_t)(i0+r)*LDIM + n*SDIM + sg*4);
        ushort4 h, l;
        h.x=f2bf(v.x); l.x=f2bf(v.x-bf2f(h.x));
        h.y=f2bf(v.y); l.y=f2bf(v.y-bf2f(h.y));
        h.z=f2bf(v.z); l.z=f2bf(v.z-bf2f(h.z));
        h.w=f2bf(v.w); l.w=f2bf(v.w-bf2f(h.w));
        int off = r*64 + ((sg*4) ^ ((r&7)<<3));   // shorts; == byte XOR (r&7)<<4
        *(ushort4*)(&Ah[off]) = h;
        *(ushort4*)(&Al[off]) = l;
    }

    const unsigned short* ehn = eh + (size_t)n*KC*SDIM;
    const unsigned short* eln = el + (size_t)n*KC*SDIM;
    const float* e2n = e2 + n*KC;

    // e2 preload (biased), 1024 floats
#pragma unroll
    for (int s=0;s<4;s++){
        int idx = tid + s*256;
        e2s[idx] = e2n[idx] + DBIAS;
    }

    unsigned int k1[16], k2[16];
#pragma unroll
    for (int j=0;j<16;j++){ k1[j]=0xFFFFFFFFu; k2[j]=0xFFFFFFFFu; }

    const int jb = wid * 256;            // wave-private code base

    // B fragment regs: [buf][nt][t], 1-deep prefetch double-buffer
    bf16x8 bhb[2][2][2], blb[2][2][2];
#pragma unroll
    for (int nt=0;nt<2;nt++){
        const size_t rb = (size_t)(jb + nt*16 + c) * SDIM;
#pragma unroll
        for (int t=0;t<2;t++){
            bhb[0][nt][t] = *(const bf16x8*)(ehn + rb + t*32 + qq*8);
            blb[0][nt][t] = *(const bf16x8*)(eln + rb + t*32 + qq*8);
        }
    }

    __syncthreads();   // A + e2s published (ONLY pre-merge barrier)

#pragma unroll
    for (int jt=0; jt<8; jt++){
        const int cur = jt & 1, nxt = cur ^ 1;
        const int j0 = jb + jt*32;

        // prefetch next tile into the other reg buffer (compile-time index)
        if (jt < 7){
#pragma unroll
            for (int nt=0;nt<2;nt++){
                const size_t rb = (size_t)(j0 + 32 + nt*16 + c) * SDIM;
#pragma unroll
                for (int t=0;t<2;t++){
                    bhb[nxt][nt][t] = *(const bf16x8*)(ehn + rb + t*32 + qq*8);
                    blb[nxt][nt][t] = *(const bf16x8*)(eln + rb + t*32 + qq*8);
                }
            }
        }

        floatx4 acc[4][2];
#pragma unroll
        for (int mt=0;mt<4;mt++){
            acc[mt][0]=(floatx4){0.f,0.f,0.f,0.f};
            acc[mt][1]=(floatx4){0.f,0.f,0.f,0.f};
        }

#pragma unroll
        for (int t=0;t<2;t++){
            const int axo = (t*32 + qq*8) ^ ((c&7)<<3);   // shorts
            bf16x8 ah[4], alo[4];
#pragma unroll
            for (int mt=0;mt<4;mt++){
                int ro = (mt*16 + c)*64 + axo;            // rows 0..63
                ah[mt]  = *(const bf16x8*)(&Ah[ro]);
                alo[mt] = *(const bf16x8*)(&Al[ro]);
            }
#pragma unroll
            for (int mt=0;mt<4;mt++)
#pragma unroll
                for (int nt=0;nt<2;nt++){
                    acc[mt][nt] = __builtin_amdgcn_mfma_f32_16x16x32_bf16(ah[mt],  bhb[cur][nt][t], acc[mt][nt], 0,0,0);
                    acc[mt][nt] = __builtin_amdgcn_mfma_f32_16x16x32_bf16(ah[mt],  blb[cur][nt][t], acc[mt][nt], 0,0,0);
                    acc[mt][nt] = __builtin_amdgcn_mfma_f32_16x16x32_bf16(alo[mt], bhb[cur][nt][t], acc[mt][nt], 0,0,0);
                }
        }

        // biased dist -> packed key -> branchless top-2 (min + med3)
#pragma unroll
        for (int nt=0;nt<2;nt++){
            const int colb = j0 + nt*16 + c;              // global code idx
            float e2v = e2s[colb];
            unsigned int kidx = (unsigned int)colb;
#pragma unroll
            for (int mt=0;mt<4;mt++)
#pragma unroll
                for (int reg=0;reg<4;reg++){
                    float d = fmaf(-2.0f, acc[mt][nt][reg], e2v);
                    unsigned int key = (__float_as_uint(d) & 0xFFFFFC00u) | kidx;
                    int s = mt*4+reg;
                    unsigned int o1 = k1[s], o2 = k2[s];
                    unsigned int nk2;
                    asm("v_med3_u32 %0, %1, %2, %3" : "=v"(nk2) : "v"(o1), "v"(o2), "v"(key));
                    k2[s] = nk2;                 // 2nd-smallest of {k1,k2,key}
                    k1[s] = min(o1, key);
                }
        }
    }

    // butterfly top-2 merge across the 16 col-lanes (wave-private result)
#pragma unroll
    for (int off=1; off<16; off<<=1){
#pragma unroll
        for (int s=0;s<16;s++){
            unsigned int o1 = __shfl_xor(k1[s], off);
            unsigned int o2 = __shfl_xor(k2[s], off);
            unsigned int n1 = min(k1[s], o1);
            k2[s] = min( max(k1[s], o1), min(k2[s], o2) );
            k1[s] = n1;
        }
    }
    if (c == 0){
#pragma unroll
        for (int s=0;s<16;s++){
            int row = (s>>2)*16 + qq*4 + (s&3);           // rows 0..63
            mK[wid][row][0] = k1[s]; mK[wid][row][1] = k2[s];
        }
    }
    __syncthreads();

    if (tid < 64){
        int b = i0 + tid;
        unsigned int f1 = mK[0][tid][0], f2 = mK[0][tid][1];
#pragma unroll
        for (int w=1; w<4; w++){
            unsigned int b1 = mK[w][tid][0], b2 = mK[w][tid][1];
            unsigned int n1 = min(f1, b1);
            f2 = min( max(f1, b1), min(f2, b2) );
            f1 = n1;
        }
        int ii1 = (int)(f1 & 0x3FFu);
        int ii2 = (int)(f2 & 0x3FFu);
        float d1q = __uint_as_float(f1 & 0xFFFFFC00u);
        float d2q = __uint_as_float(f2 & 0xFFFFFC00u);

        const float* eb = emb + (size_t)n*KC*SDIM;
        const float* zg = z + (size_t)b*LDIM + n*SDIM;
        if (d2q - d1q < 0.08f) {   // window covers quantization (0.031) + bf16 err
            double d1 = dist64d(eb + (size_t)ii1*SDIM, zg);
            double d2 = dist64d(eb + (size_t)ii2*SDIM, zg);
            if (d2 < d1 || (d2 == d1 && ii2 < ii1)) ii1 = ii2;
        }

        const float4* q4 = (const float4*)(eb + (size_t)ii1*SDIM);
        const float4* z4 = (const float4*)zg;
        float4* oq = (float4*)(out_q + (size_t)b*LDIM + n*SDIM);
        float cs = 0.f;
#pragma unroll
        for (int i=0;i<16;i++){
            float4 v = q4[i]; float4 zv = z4[i];
            oq[i] = v;
            float d0=v.x-zv.x, d1=v.y-zv.y, d2=v.z-zv.z, d3=v.w-zv.w;
            cs += d0*d0 + d1*d1 + d2*d2 + d3*d3;
        }
        out_idx[b*NCB + n] = (float)ii1;

        for (int off=32; off; off>>=1) cs += __shfl_down(cs, off);
        if (tid == 0) atomicAdd(&accs[0], cs);
    }
}

// ---------------------------------------------------------------------------
// K3: per-row L2 norms; write normalized FP8 (e4m3) copies + diag.
// Wave-per-row (4 rows/block), zero barriers, zero LDS, packed stores.
// ---------------------------------------------------------------------------
__global__ __launch_bounds__(256) void
k_norm(const float* __restrict__ z, const float* __restrict__ q,
       unsigned char* __restrict__ zn8, unsigned char* __restrict__ qn8,
       float* __restrict__ diag) {
    const int wid = threadIdx.x >> 6, lane = threadIdx.x & 63;
    const int b = blockIdx.x*4 + wid;
    const size_t base = (size_t)b*LDIM;
    const float4* z4 = (const float4*)(z + base + lane*8);
    const float4* q4 = (const float4*)(q + base + lane*8);
    float4 za = z4[0], zb = z4[1];
    float4 qa = q4[0], qb = q4[1];
    float sz = za.x*za.x + za.y*za.y + za.z*za.z + za.w*za.w
             + zb.x*zb.x + zb.y*zb.y + zb.z*zb.z + zb.w*zb.w;
    float sq = qa.x*qa.x + qa.y*qa.y + qa.z*qa.z + qa.w*qa.w
             + qb.x*qb.x + qb.y*qb.y + qb.z*qb.z + qb.w*qb.w;
    float sqz= qa.x*za.x + qa.y*za.y + qa.z*za.z + qa.w*za.w
             + qb.x*zb.x + qb.y*zb.y + qb.z*zb.z + qb.w*zb.w;
#pragma unroll
    for (int off=1; off<64; off<<=1){
        sz  += __shfl_xor(sz,  off);
        sq  += __shfl_xor(sq,  off);
        sqz += __shfl_xor(sqz, off);
    }
    float inz = 1.0f/fmaxf(sqrtf(sz), 1e-12f);
    float inq = 1.0f/fmaxf(sqrtf(sq), 1e-12f);
    if (lane == 0) diag[b] = sqz*inz*inq*INV_TAU;

    int z0 = __builtin_amdgcn_cvt_pk_fp8_f32(za.x*inz, za.y*inz, 0, false);
    z0     = __builtin_amdgcn_cvt_pk_fp8_f32(za.z*inz, za.w*inz, z0, true);
    int z1 = __builtin_amdgcn_cvt_pk_fp8_f32(zb.x*inz, zb.y*inz, 0, false);
    z1     = __builtin_amdgcn_cvt_pk_fp8_f32(zb.z*inz, zb.w*inz, z1, true);
    int q0 = __builtin_amdgcn_cvt_pk_fp8_f32(qa.x*inq, qa.y*inq, 0, false);
    q0     = __builtin_amdgcn_cvt_pk_fp8_f32(qa.z*inq, qa.w*inq, q0, true);
    int q1 = __builtin_amdgcn_cvt_pk_fp8_f32(qb.x*inq, qb.y*inq, 0, false);
    q1     = __builtin_amdgcn_cvt_pk_fp8_f32(qb.z*inq, qb.w*inq, q1, true);
    uint2 uz; uz.x = (unsigned)z0; uz.y = (unsigned)z1;
    uint2 uq; uq.x = (unsigned)q0; uq.y = (unsigned)q1;
    *(uint2*)(zn8 + base + lane*8) = uz;
    *(uint2*)(qn8 + base + lane*8) = uq;
}

// ---------------------------------------------------------------------------
// K4: logsumexp of logits = qn8 · zn8^T / TAU via MX-scaled fp8 MFMA
// 16x16x128 (scales=1.0). R6 build verbatim (best measured): 512-col
// chunks, grid (64,16) = 4 blocks/CU, XCD pin chnk=(bx&7)+8*(by&1),
// af[2][4] asm-pinned, nt-outer MFMA, gll dbuf B, 16 phases.
// ---------------------------------------------------------------------------
__global__ __launch_bounds__(256,4) void
k_logits(const unsigned char* __restrict__ qn8, const unsigned char* __restrict__ zn8,
         float* __restrict__ Spart) {
    __shared__ __align__(16) unsigned char Bs[2][32*512];
    const int tid  = threadIdx.x;
    // XCD pin: chnk from bx&7 (XCD id) + one by bit; row-tile from the rest.
    const int chnk = (blockIdx.x & 7) + ((blockIdx.y & 1) << 3);   // 0..15, 512 cols
    const int i0   = (((blockIdx.x >> 3) << 3) + (blockIdx.y >> 1)) * 128;
    const int wid  = tid >> 6, lane = tid & 63;
    const int wm = wid;                    // 4 m-groups of 32 rows
    const int c  = lane & 15, qq = lane >> 4;

    // gll lane geometry: 2 rows x 512B per wave-instr; source pre-swizzled
    const int brow  = lane >> 5;
    const int bchk0 = (lane & 31) * 16;

    auto stageB = [&](int buf, int j0){
#pragma unroll
        for (int s=0;s<4;s++){
            int r0  = wid*8 + s*2;
            int row = r0 + brow;
            gll16(zn8 + (size_t)(j0+row)*LDIM + (bchk0 ^ ((row&7)<<4)),
                  &Bs[buf][r0*512]);
        }
    };

    stageB(0, chnk*512);   // async; drained by the pre-loop barrier

    // ---- A resident in regs: 2 mt x 4 kc fragments (rows i0+wm*32+mt*16+c)
    intx8 af[2][4];
#pragma unroll
    for (int mt=0;mt<2;mt++){
        const unsigned char* ap = qn8 + (size_t)(i0 + wm*32 + mt*16 + c)*LDIM + qq*32;
#pragma unroll
        for (int kc=0;kc<4;kc++){
            union { intx8 v; uint4 h[2]; } u;
            u.h[0] = *(const uint4*)(ap + kc*128);
            u.h[1] = *(const uint4*)(ap + kc*128 + 16);
            af[mt][kc] = u.v;
        }
    }
    // pin af: opaque def makes rematerialization impossible (R4 lesson)
#pragma unroll
    for (int mt=0;mt<2;mt++)
#pragma unroll
        for (int kc=0;kc<4;kc++)
            asm volatile("" : "+v"(af[mt][kc]));

    float S[8];
#pragma unroll
    for (int i=0;i<8;i++) S[i] = 0.f;

    __syncthreads();        // drains stageB(0), publishes buf 0

    for (int jt=0;jt<16;jt++){
        const int cur = jt & 1;
        const int j0 = chnk*512 + jt*32;
        if (jt < 15) stageB(cur^1, j0 + 32);   // async prefetch next tile

        floatx4 acc[2][2];
#pragma unroll
        for (int mt=0;mt<2;mt++){
            acc[mt][0]=(floatx4){0.f,0.f,0.f,0.f};
            acc[mt][1]=(floatx4){0.f,0.f,0.f,0.f};
        }

#pragma unroll
        for (int kc=0;kc<4;kc++)
#pragma unroll
            for (int nt=0;nt<2;nt++){
                const int rb = nt*16 + c;          // tile row 0..31
                const unsigned char* p = &Bs[cur][rb*512];
                const int o = kc*128 + qq*32;
                const int x = (rb&7)<<4;
                union { intx8 v; uint4 h[2]; } u;
                u.h[0] = *(const uint4*)(p + (o ^ x));
                u.h[1] = *(const uint4*)(p + ((o + 16) ^ x));
                intx8 bfr = u.v;
#pragma unroll
                for (int mt=0;mt<2;mt++)
                    acc[mt][nt] = __builtin_amdgcn_mfma_scale_f32_16x16x128_f8f6f4(
                        af[mt][kc], bfr, acc[mt][nt],
                        0, 0,        // cbsz=FP8(e4m3), blgp=FP8(e4m3)
                        0, 127,      // scale_a opsel, scale_a (e8m0 1.0)
                        0, 127);     // scale_b opsel, scale_b
            }

        // S[row-slot] += sum_nt 2^((dot-1)*K2E)
#pragma unroll
        for (int mt=0;mt<2;mt++)
#pragma unroll
            for (int reg=0;reg<4;reg++){
                float e0 = exp2_fast(fmaf(acc[mt][0][reg], K2E, -K2E));
                float e1 = exp2_fast(fmaf(acc[mt][1][reg], K2E, -K2E));
                S[mt*4+reg] += e0 + e1;
            }
        __syncthreads();   // drains gll prefetch, publishes next buffer
    }

    // reduce over the 16 col-lanes (disjoint cols, same rows)
#pragma unroll
    for (int off=1; off<16; off<<=1)
#pragma unroll
        for (int s=0;s<8;s++) S[s] += __shfl_xor(S[s], off);

    if (c == 0){
        const int p = chnk;                    // 16 partial slots
#pragma unroll
        for (int mt=0;mt<2;mt++)
#pragma unroll
            for (int reg=0;reg<4;reg++){
                int row = i0 + wm*32 + mt*16 + qq*4 + reg;
                Spart[p*BATCH + row] = S[mt*4+reg];
            }
    }
}

// ---------------------------------------------------------------------------
// K5: combine 16 partials/row -> LSE - diag, reduce to accs[1]; the LAST
// block (device-scope counter accs[2]) also writes the two output scalars.
// ---------------------------------------------------------------------------
__global__ __launch_bounds__(256) void
k_finalize(const float* __restrict__ Spart, const float* __restrict__ diag,
           float* __restrict__ accs, float* __restrict__ out_s) {
    int r = blockIdx.x*256 + threadIdx.x;
    float Ssum = 0.f;
#pragma unroll
    for (int p=0;p<16;p++) Ssum += Spart[p*BATCH + r];
    float val = INV_TAU + logf(Ssum) - diag[r];
    for (int off=32; off; off>>=1) val += __shfl_down(val, off);
    if ((threadIdx.x & 63)==0) atomicAdd(&accs[1], val);
    __syncthreads();                       // drains this block's atomics
    if (threadIdx.x == 0){
        __threadfence();
        unsigned int old = __float_as_uint(atomicAdd(&accs[2], 1.0f));
        if (old == __float_as_uint(31.0f)) {   // 32nd (last) block
            __threadfence();
            float a0 = atomicAdd(&accs[0], 0.0f);
            float a1 = atomicAdd(&accs[1], 0.0f);
            out_s[0] = 2.0f*a0 / (float)((size_t)BATCH*LDIM);   // commit+embed
            out_s[1] = a1 / (float)BATCH;                       // contrastive
        }
    }
}

// ---------------------------------------------------------------------------
extern "C" void kernel_launch(void* const* d_in, const int* in_sizes, int n_in,
                              void* d_out, int out_size, void* d_ws, size_t ws_size,
                              hipStream_t stream) {
    const float* z   = (const float*)d_in[0];   // (B, L)
    const float* emb = (const float*)d_in[1];   // (NC, K, SD)
    float* out = (float*)d_out;
    float* out_q       = out;                   // B*L = 4194304
    float* out_scalars = out + 4194304;         // [commit, contrastive]
    float* out_idx     = out + 4194306;         // B*NC as float

    // ws layout (float offsets); ~11 MB total
    float* wsf   = (float*)d_ws;
    float* e2    = wsf;                         // 8192
    float* accs  = wsf + 8192;                  // [commit, contrastive, counter]
    float* diag  = wsf + 8704;                  // 8192
    float* Spart = wsf + 16896;                 // 16 slots used (32 reserved)
    unsigned char* qn8 = (unsigned char*)(Spart + 32*BATCH);   // B*L fp8 (4 MB)
    unsigned char* zn8 = qn8 + (size_t)BATCH*LDIM;             // B*L fp8 (4 MB)
    unsigned short* eh = (unsigned short*)(zn8 + (size_t)BATCH*LDIM); // NC*K*SD bf16
    unsigned short* el = eh + (size_t)NCB*KC*SDIM;             // NC*K*SD bf16

    k_pre    <<<256,         256, 0, stream>>>(emb, e2, eh, el, accs);
    k_argmin <<<dim3(128,8), 256, 0, stream>>>(eh, el, e2, z, emb,
                                               out_q, out_idx, accs);
    k_norm   <<<2048,        256, 0, stream>>>(z, out_q, zn8, qn8, diag);
    k_logits <<<dim3(64,16), 256, 0, stream>>>(qn8, zn8, Spart);
    k_finalize<<<32,         256, 0, stream>>>(Spart, diag, accs, out_scalars);
}